// Round 6
// baseline (22.076 us; speedup 1.0000x reference)
//
#include <hip/hip_runtime.h>
#include <hip/hip_bf16.h>

// Problem constants (fixed by the reference)
#define IN_DIM    128
#define OUT_DIM   64
#define NUM_BASIS 8
#define SEQ       512
#define BATCH     2
#define EPS       1e-5f
#define SX        2     // sequence positions per block

// ---------------------------------------------------------------------------
// Wave-specialized fused kernel: 256 blocks x 512 threads (1 block/CU,
// 2 waves/SIMD: one ph1-wave + one Wgen-wave per SIMD).
//
// Waves 0..3 (ph1): wave r owns row (sl=r>>1, b=r&1). Lane o computes the
//   full 128-dim dots x@M[o]^T and x@Wres[o]^T (x read wave-uniform from
//   global -> L1 broadcast). LayerNorm is wave-internal (64-lane butterfly
//   == the o axis), so NO block barrier is needed before publishing
//   xts/rs to LDS. Publication is signalled via an LDS ready-flag.
//
// Waves 4..7 (Wgen): wave g owns j in [16g, 16g+16), i = lane.
//   W[s,i,j] = sum_g P[i,j,g]*cos(2*pi*k_s/((i*64+j)*8+g+2)); rcp(period)
//   is s-independent (shared for s0,s1); cos(2*pi*t)==v_cos_f32(fract(t)).
//   16 j's/wave keeps the per-SIMD trans budget identical to the symmetric
//   kernel (384 trans * 8cyc = 3072 cyc) but ph1 now hides entirely under
//   it. After W-gen, spin on the ready-flag (ph1 finishes long before),
//   then contract with xts and write partials.
//
// One converged __syncthreads before the final 4-way partial reduce.
// ---------------------------------------------------------------------------
__global__ __launch_bounds__(512) void fused_layerts_kernel(
    const float* __restrict__ x,         // (B, S, 128)
    const float* __restrict__ M,         // (64, 128)
    const float* __restrict__ Wres,      // (64, 128)
    const float* __restrict__ gamma,     // (64)
    const float* __restrict__ beta,      // (64)
    const float* __restrict__ P,         // (64, 64, 8)
    const int*   __restrict__ positions, // (S)
    float* __restrict__ out)             // (B, S, 64)
{
    const int s0   = blockIdx.x * SX;
    const int tid  = threadIdx.x;
    const int lane = tid & 63;
    const int wv   = tid >> 6;           // 0..7

    __shared__ float xts[SX][BATCH][OUT_DIM];       // normalized projections
    __shared__ float rs [SX][BATCH][OUT_DIM];       // residual projections
    __shared__ float part[4][SX][BATCH][OUT_DIM];   // Wgen-wave partials (4 KB)
    __shared__ int   ready;

    if (tid == 0) ready = 0;
    __syncthreads();                     // publish ready=0 to all waves

    const float k0 = (float)positions[s0];
    const float k1 = (float)positions[s0 + 1];

    if (wv < 4) {
        // ================= ph1 waves: projections + LayerNorm =============
        const int r  = wv;
        const int b  = r & 1;
        const int sl = r >> 1;
        const int o  = lane;

        const float4* x4 = reinterpret_cast<const float4*>(
            x + ((size_t)b * SEQ + (s0 + sl)) * IN_DIM);          // wave-uniform
        const float4* m4 = reinterpret_cast<const float4*>(M    + (size_t)o * IN_DIM);
        const float4* w4 = reinterpret_cast<const float4*>(Wres + (size_t)o * IN_DIM);

        // dual accumulators: halve the serial FMA chain
        float ma = 0.f, mb = 0.f, ra = 0.f, rb = 0.f;
#pragma unroll
        for (int c = 0; c < 32; c += 2) {
            float4 xv0 = x4[c],     mv0 = m4[c],     wv0 = w4[c];
            float4 xv1 = x4[c + 1], mv1 = m4[c + 1], wv1 = w4[c + 1];
            ma += xv0.x * mv0.x + xv0.y * mv0.y + xv0.z * mv0.z + xv0.w * mv0.w;
            ra += xv0.x * wv0.x + xv0.y * wv0.y + xv0.z * wv0.z + xv0.w * wv0.w;
            mb += xv1.x * mv1.x + xv1.y * mv1.y + xv1.z * mv1.z + xv1.w * mv1.w;
            rb += xv1.x * wv1.x + xv1.y * wv1.y + xv1.z * wv1.z + xv1.w * wv1.w;
        }
        const float macc = ma + mb;
        const float racc = ra + rb;

        // wave-internal LayerNorm over the 64 output channels (== lanes)
        float ssum = macc;
#pragma unroll
        for (int off = 32; off > 0; off >>= 1) ssum += __shfl_xor(ssum, off);
        const float mu = ssum * (1.0f / OUT_DIM);

        const float d = macc - mu;
        float v = d * d;
#pragma unroll
        for (int off = 32; off > 0; off >>= 1) v += __shfl_xor(v, off);
        const float var = v * (1.0f / OUT_DIM);

        xts[sl][b][o] = d * rsqrtf(var + EPS) * gamma[o] + beta[o];
        rs [sl][b][o] = racc;

        __threadfence_block();           // drain ds_writes (wave-level waitcnt)
        if (lane == 0)
            __hip_atomic_fetch_add(&ready, 1, __ATOMIC_RELEASE,
                                   __HIP_MEMORY_SCOPE_WORKGROUP);
    } else {
        // ================= Wgen waves: W generation + contraction =========
        const int g = wv - 4;            // 0..3, owns j in [16g, 16g+16)
        const int i = lane;

        float w0[16], w1[16];            // statically indexed (full unroll)
#pragma unroll
        for (int jj = 0; jj < 16; ++jj) {
            const int j    = g * 16 + jj;
            const int base = (i * OUT_DIM + j) * NUM_BASIS;   // flat (i,j,0)
            const float4* Pp = reinterpret_cast<const float4*>(P + base);
            const float4 p0 = Pp[0];
            const float4 p1 = Pp[1];
            const float basef = (float)(base + 2);            // exact in f32

            const float pv[8] = {p0.x, p0.y, p0.z, p0.w, p1.x, p1.y, p1.z, p1.w};
            float a0 = 0.f, a1 = 0.f;
#pragma unroll
            for (int gg = 0; gg < NUM_BASIS; ++gg) {
                const float inv = __builtin_amdgcn_rcpf(basef + (float)gg);
                a0 += pv[gg] * __builtin_amdgcn_cosf(__builtin_amdgcn_fractf(k0 * inv));
                a1 += pv[gg] * __builtin_amdgcn_cosf(__builtin_amdgcn_fractf(k1 * inv));
            }
            w0[jj] = a0;
            w1[jj] = a1;
        }

        // wait until all 4 ph1 waves published xts/rs (they finish earlier)
        while (__hip_atomic_load(&ready, __ATOMIC_ACQUIRE,
                                 __HIP_MEMORY_SCOPE_WORKGROUP) < 4) {
            __builtin_amdgcn_s_sleep(1);
        }

        float nk00 = 0.f, nk01 = 0.f, nk10 = 0.f, nk11 = 0.f;
#pragma unroll
        for (int jj = 0; jj < 16; ++jj) {
            const int j = g * 16 + jj;   // wave-uniform -> LDS broadcast
            nk00 += xts[0][0][j] * w0[jj];
            nk01 += xts[0][1][j] * w0[jj];
            nk10 += xts[1][0][j] * w1[jj];
            nk11 += xts[1][1][j] * w1[jj];
        }
        part[g][0][0][i] = nk00;
        part[g][0][1][i] = nk01;
        part[g][1][0][i] = nk10;
        part[g][1][1][i] = nk11;
    }

    __syncthreads();                     // converged: all waves arrive once

    // ---- epilogue: reduce the 4 Wgen partials, add residual, store ----
    if (tid < SX * BATCH * OUT_DIM) {
        const int o  = tid & 63;
        const int r  = tid >> 6;
        const int b  = r & 1;
        const int sl = r >> 1;

        const float sum = part[0][sl][b][o] + part[1][sl][b][o] +
                          part[2][sl][b][o] + part[3][sl][b][o];

        const size_t idx = ((size_t)b * SEQ + (s0 + sl)) * OUT_DIM + o;
        out[idx] = sum + rs[sl][b][o];
    }
}

// ---------------------------------------------------------------------------
extern "C" void kernel_launch(void* const* d_in, const int* in_sizes, int n_in,
                              void* d_out, int out_size, void* d_ws, size_t ws_size,
                              hipStream_t stream)
{
    const float* x         = (const float*)d_in[0];
    const int*   positions = (const int*)d_in[1];
    const float* M         = (const float*)d_in[2];
    const float* P         = (const float*)d_in[3];
    const float* gamma     = (const float*)d_in[4];
    const float* beta      = (const float*)d_in[5];
    const float* Wres      = (const float*)d_in[6];
    float* out = (float*)d_out;

    hipLaunchKernelGGL(fused_layerts_kernel, dim3(SEQ / SX), dim3(512), 0, stream,
                       x, M, Wres, gamma, beta, P, positions, out);
}

// Round 7
// 18.109 us; speedup vs baseline: 1.2191x; 1.2191x over previous
//
#include <hip/hip_runtime.h>
#include <hip/hip_bf16.h>

// Problem constants (fixed by the reference)
#define IN_DIM    128
#define OUT_DIM   64
#define NUM_BASIS 8
#define SEQ       512
#define BATCH     2
#define EPS       1e-5f
#define SX        2     // sequence positions per block

// ---------------------------------------------------------------------------
// Fully fused, 2 sequence positions per block: 256 blocks x 512 threads
// (~1 block/CU, 2 waves/SIMD).  R5 structure == best measured (18.13us).
// R4 (load/cos interleave) and R6 (wave specialization) both regressed:
// the trans pipe needs BOTH waves/SIMD issuing cos to stay saturated.
//
// Phase 1 (all 512 threads): half-row dot products for the M-projection and
//   the Wres residual projection, combined via LDS; LayerNorm via 64-lane
//   shfl butterfly (lane == output channel).  Dual accumulators halve the
//   serial FMA chain on the latency-exposed M/Wres load stream.
// Phase 2 (all 512 threads): i = tid&63, grp = tid>>6 owns 8 j's.
//   W[s,i,j] = sum_g P[i,j,g] * cos(2*pi*k_s / ((i*64+j)*8 + g + 2))
//   rcp(period) is s-independent -> computed once, cos per s.
//   cos(2*pi*t) == v_cos_f32(fract(t)) (hardware cos takes revolutions).
//   Contraction fused directly after W-gen (xts ready before phase 2).
// ---------------------------------------------------------------------------
__global__ __launch_bounds__(512) void fused_layerts_kernel(
    const float* __restrict__ x,         // (B, S, 128)
    const float* __restrict__ M,         // (64, 128)
    const float* __restrict__ Wres,      // (64, 128)
    const float* __restrict__ gamma,     // (64)
    const float* __restrict__ beta,      // (64)
    const float* __restrict__ P,         // (64, 64, 8)
    const int*   __restrict__ positions, // (S)
    float* __restrict__ out)             // (B, S, 64)
{
    const int s0  = blockIdx.x * SX;     // first seq position of this block
    const int tid = threadIdx.x;

    __shared__ float xs [SX][BATCH][IN_DIM];          // x rows (2 KB)
    __shared__ float xts[SX][BATCH][OUT_DIM];         // normalized projections
    __shared__ float rs [SX][BATCH][OUT_DIM];         // residual projections
    __shared__ float pm [2][SX * BATCH][OUT_DIM];     // phase-1 partials (M)
    __shared__ float pr [2][SX * BATCH][OUT_DIM];     // phase-1 partials (Wres)
    __shared__ float part[8][SX][BATCH][OUT_DIM];     // phase-2 partials (8 KB)

    // ---- load the 4 x-rows (SX*BATCH*IN_DIM = 512 floats, 1/thread) ----
    {
        const int row = tid >> 7;        // 0..3  = (sl, b)
        const int c   = tid & 127;
        const int b   = row & 1;
        const int sl  = row >> 1;
        xs[sl][b][c] = x[((size_t)b * SEQ + (s0 + sl)) * IN_DIM + c];
    }
    const float k0 = (float)positions[s0];
    const float k1 = (float)positions[s0 + 1];
    __syncthreads();

    // ---- Phase 1a: half-row dot products (all 512 threads) ----
    {
        const int o    = tid & 63;           // output channel
        const int r    = (tid >> 6) & 3;     // (sl<<1)|b
        const int half = tid >> 8;           // channel half 0..1
        const int b    = r & 1;
        const int sl   = r >> 1;

        const float4* x4 = reinterpret_cast<const float4*>(&xs[sl][b][half * 64]);
        const float4* m4 = reinterpret_cast<const float4*>(M    + (size_t)o * IN_DIM + half * 64);
        const float4* w4 = reinterpret_cast<const float4*>(Wres + (size_t)o * IN_DIM + half * 64);

        // dual accumulators: halves the serial FMA dependency chain
        float macc0 = 0.f, macc1 = 0.f, racc0 = 0.f, racc1 = 0.f;
#pragma unroll
        for (int c = 0; c < 16; c += 2) {
            float4 xv0 = x4[c],     mv0 = m4[c],     wv0 = w4[c];
            float4 xv1 = x4[c + 1], mv1 = m4[c + 1], wv1 = w4[c + 1];
            macc0 += xv0.x * mv0.x + xv0.y * mv0.y + xv0.z * mv0.z + xv0.w * mv0.w;
            racc0 += xv0.x * wv0.x + xv0.y * wv0.y + xv0.z * wv0.z + xv0.w * wv0.w;
            macc1 += xv1.x * mv1.x + xv1.y * mv1.y + xv1.z * mv1.z + xv1.w * mv1.w;
            racc1 += xv1.x * wv1.x + xv1.y * wv1.y + xv1.z * wv1.z + xv1.w * wv1.w;
        }
        pm[half][r][o] = macc0 + macc1;
        pr[half][r][o] = racc0 + racc1;
    }
    __syncthreads();

    // ---- Phase 1b: combine halves + LayerNorm (threads 0..255) ----
    if (tid < SX * BATCH * OUT_DIM) {
        const int o  = tid & 63;
        const int r  = tid >> 6;             // wave id == r, lanes == o
        const int b  = r & 1;
        const int sl = r >> 1;

        const float macc = pm[0][r][o] + pm[1][r][o];
        const float racc = pr[0][r][o] + pr[1][r][o];

        float ssum = macc;
#pragma unroll
        for (int off = 32; off > 0; off >>= 1) ssum += __shfl_xor(ssum, off);
        const float mu = ssum * (1.0f / OUT_DIM);

        const float d = macc - mu;
        float v = d * d;
#pragma unroll
        for (int off = 32; off > 0; off >>= 1) v += __shfl_xor(v, off);
        const float var = v * (1.0f / OUT_DIM);

        xts[sl][b][o] = d * rsqrtf(var + EPS) * gamma[o] + beta[o];
        rs [sl][b][o] = racc;
    }
    __syncthreads();

    // ---- Phase 2: W generation + contraction (all 512 threads) ----
    const int i   = tid & 63;
    const int grp = tid >> 6;                // 0..7, owns 8 j's

    float nk00 = 0.f, nk01 = 0.f, nk10 = 0.f, nk11 = 0.f;

#pragma unroll
    for (int jj = 0; jj < 8; ++jj) {
        const int j    = grp * 8 + jj;
        const int base = (i * OUT_DIM + j) * NUM_BASIS;   // flat (i,j,0)
        const float4* Pp = reinterpret_cast<const float4*>(P + base);
        const float4 p0 = Pp[0];
        const float4 p1 = Pp[1];
        const float basef = (float)(base + 2);            // period at g=0 (exact in f32)

        const float pv[8] = {p0.x, p0.y, p0.z, p0.w, p1.x, p1.y, p1.z, p1.w};
        float w0 = 0.f, w1 = 0.f;
#pragma unroll
        for (int g = 0; g < NUM_BASIS; ++g) {
            const float period = basef + (float)g;
            const float inv = __builtin_amdgcn_rcpf(period);     // s-independent
            float t0 = __builtin_amdgcn_fractf(k0 * inv);
            float t1 = __builtin_amdgcn_fractf(k1 * inv);
            w0 += pv[g] * __builtin_amdgcn_cosf(t0);             // cos(2*pi*t)
            w1 += pv[g] * __builtin_amdgcn_cosf(t1);
        }
        nk00 += xts[0][0][j] * w0;
        nk01 += xts[0][1][j] * w0;
        nk10 += xts[1][0][j] * w1;
        nk11 += xts[1][1][j] * w1;
    }

    part[grp][0][0][i] = nk00;
    part[grp][0][1][i] = nk01;
    part[grp][1][0][i] = nk10;
    part[grp][1][1][i] = nk11;
    __syncthreads();

    // ---- Epilogue: reduce partials, add residual, store (threads 0..255) ----
    if (tid < SX * BATCH * OUT_DIM) {
        const int o  = tid & 63;
        const int r  = tid >> 6;
        const int b  = r & 1;
        const int sl = r >> 1;

        float sum = 0.f;
#pragma unroll
        for (int gg = 0; gg < 8; ++gg) sum += part[gg][sl][b][o];

        const size_t idx = ((size_t)b * SEQ + (s0 + sl)) * OUT_DIM + o;
        out[idx] = sum + rs[sl][b][o];
    }
}

// ---------------------------------------------------------------------------
extern "C" void kernel_launch(void* const* d_in, const int* in_sizes, int n_in,
                              void* d_out, int out_size, void* d_ws, size_t ws_size,
                              hipStream_t stream)
{
    const float* x         = (const float*)d_in[0];
    const int*   positions = (const int*)d_in[1];
    const float* M         = (const float*)d_in[2];
    const float* P         = (const float*)d_in[3];
    const float* gamma     = (const float*)d_in[4];
    const float* beta      = (const float*)d_in[5];
    const float* Wres      = (const float*)d_in[6];
    float* out = (float*)d_out;

    hipLaunchKernelGGL(fused_layerts_kernel, dim3(SEQ / SX), dim3(512), 0, stream,
                       x, M, Wres, gamma, beta, P, positions, out);
}